// Round 1
// baseline (534.158 us; speedup 1.0000x reference)
//
#include <hip/hip_runtime.h>
#include <stdint.h>

typedef unsigned short u16;
typedef unsigned int u32;

#define T_TOK 8192      // B*S tokens
#define DIMSZ 1024
#define HIDSZ 1024
#define NE 8
#define NSLOT (T_TOK * 2)
#define NPAD (NSLOT + 1024)   // segment-aligned slot capacity
// NOTE: 256-row GEMM tiles may over-READ up to 255 rows past a segment's
// padded end; those reads land in the adjacent workspace buffer (benign,
// results masked on write), so NPAD does not need to grow.

typedef __attribute__((ext_vector_type(8))) __bf16 bf16x8;
typedef __attribute__((ext_vector_type(16))) float f32x16;

#define MFMA32(a, b, c) __builtin_amdgcn_mfma_f32_32x32x16_bf16(a, b, c, 0, 0, 0)

// ---- blocked tile layouts (all GEMM operands, K = 1024, KT = 32) ----------
// A (activations, 128-row tiles):  [mt][kt][kc][row(128)][8]  (8 KB / tile)
// W (weights, 64-row tiles):       [nt][kt][kc][col(64)][8]   (4 KB / tile)
// Staging a tile = flat memcpy: global tile bytes == LDS tile bytes.
__device__ __forceinline__ size_t ablk(int pos, int c) {
  return ((((size_t)(pos >> 7) * 32 + (c >> 5)) * 4 + ((c >> 3) & 3)) * 128 +
          (pos & 127)) * 8 + (c & 7);
}

__device__ __forceinline__ u16 f2bf(float f) {
  u32 u = __builtin_bit_cast(u32, f);
  u += 0x7FFFu + ((u >> 16) & 1u);   // RNE
  return (u16)(u >> 16);
}
__device__ __forceinline__ float bflo(u32 v) { return __builtin_bit_cast(float, v << 16); }
__device__ __forceinline__ float bfhi(u32 v) { return __builtin_bit_cast(float, v & 0xffff0000u); }
__device__ __forceinline__ u32 pack2(float a, float b) {
  return (u32)f2bf(a) | ((u32)f2bf(b) << 16);
}
__device__ __forceinline__ float silu_f(float v) { return v / (1.f + expf(-v)); }

// ---- async global->LDS, 16 B per lane (global_load_lds_dwordx4) -----------
__device__ __forceinline__ void gload16(const void* g, void* l) {
  __builtin_amdgcn_global_load_lds(
      (const __attribute__((address_space(1))) unsigned int*)g,
      (__attribute__((address_space(3))) unsigned int*)l, 16, 0, 0);
}

// counted-vmcnt barrier: waits until <=N of this wave's global_load_lds are
// outstanding, then s_barrier. Single asm so nothing is scheduled between;
// "memory" clobber fences the compiler's ds_read/ds_write motion.
#define PIPE_SYNC(N) asm volatile("s_waitcnt vmcnt(" #N ")\n\ts_barrier" ::: "memory")

// ---------------- weight convert: fp32 row-major -> bf16 blocked (1 launch) --
__global__ __launch_bounds__(256) void convert_blocked(
    const float* __restrict__ s0, const float* __restrict__ s1,
    const float* __restrict__ s2, const float* __restrict__ ss0,
    const float* __restrict__ ss1, const float* __restrict__ ss2,
    u16* __restrict__ d0, u16* __restrict__ d1, u16* __restrict__ d2,
    u16* __restrict__ ds0, u16* __restrict__ ds1, u16* __restrict__ ds2) {
  __shared__ u16 lt[2048];
  int t = blockIdx.x;
  const float* s;
  u16* d;
  if (t < NE * 16 * 32) {
    s = (blockIdx.y == 0) ? s0 : (blockIdx.y == 1) ? s1 : s2;
    d = (blockIdx.y == 0) ? d0 : (blockIdx.y == 1) ? d1 : d2;
  } else {
    t -= NE * 16 * 32;
    s = (blockIdx.y == 0) ? ss0 : (blockIdx.y == 1) ? ss1 : ss2;
    d = (blockIdx.y == 0) ? ds0 : (blockIdx.y == 1) ? ds1 : ds2;
  }
  int rt = t >> 5, kt = t & 31;           // 64-row group, k-tile
  const float* sp = s + (size_t)rt * 64 * 1024 + kt * 32;
  int nl = threadIdx.x >> 2, k0 = (threadIdx.x & 3) * 8;
  float4 a = *(const float4*)(sp + (size_t)nl * 1024 + k0);
  float4 b = *(const float4*)(sp + (size_t)nl * 1024 + k0 + 4);
  uint4 p;
  p.x = pack2(a.x, a.y); p.y = pack2(a.z, a.w);
  p.z = pack2(b.x, b.y); p.w = pack2(b.z, b.w);
  *(uint4*)&lt[(threadIdx.x & 3) * 512 + nl * 8] = p;   // [kc][col][8]
  __syncthreads();
  *(uint4*)(d + (size_t)t * 2048 + threadIdx.x * 8) = *(const uint4*)&lt[threadIdx.x * 8];
}

// ---------------- router: fp32 scores, top-2; emits blocked bf16(x) ----------
__global__ __launch_bounds__(256) void router_kernel(
    const float* __restrict__ x, const float* __restrict__ gw,
    const float* __restrict__ bias, int* __restrict__ sel,
    float* __restrict__ selscore, u16* __restrict__ xb) {
  int t = blockIdx.x * 4 + (threadIdx.x >> 6);
  int lane = threadIdx.x & 63;
  float a[NE];
#pragma unroll
  for (int e = 0; e < NE; e++) a[e] = 0.f;
#pragma unroll
  for (int j = 0; j < 4; j++) {
    int c = j * 256 + lane * 4;
    float4 xv = *(const float4*)&x[(size_t)t * DIMSZ + c];
    uint2 p;
    p.x = pack2(xv.x, xv.y);
    p.y = pack2(xv.z, xv.w);
    *(uint2*)&xb[ablk(t, c)] = p;
#pragma unroll
    for (int e = 0; e < NE; e++) {
      float4 gv = *(const float4*)&gw[e * DIMSZ + c];
      a[e] = fmaf(xv.x, gv.x, fmaf(xv.y, gv.y, fmaf(xv.z, gv.z, fmaf(xv.w, gv.w, a[e]))));
    }
  }
#pragma unroll
  for (int off = 1; off < 64; off <<= 1)
#pragma unroll
    for (int e = 0; e < NE; e++) a[e] += __shfl_xor(a[e], off);
  if (lane == 0) {
    float s[NE], b[NE];
#pragma unroll
    for (int e = 0; e < NE; e++) {
      s[e] = 1.f / (1.f + expf(-a[e]));
      b[e] = s[e] + bias[e];
    }
    int e1 = 0; float v1 = b[0];
#pragma unroll
    for (int e = 1; e < NE; e++) if (b[e] > v1) { v1 = b[e]; e1 = e; }
    int e2 = -1; float v2 = -1e30f;
#pragma unroll
    for (int e = 0; e < NE; e++) if (e != e1 && b[e] > v2) { v2 = b[e]; e2 = e; }
    sel[t * 2] = e1; sel[t * 2 + 1] = e2;
    selscore[t * 2] = s[e1];       // ROUTE_SCALE == 1
    selscore[t * 2 + 1] = s[e2];
  }
}

// ---------------- rank: atomic-free permutation; 128-aligned segments --------
__global__ __launch_bounds__(1024) void rank_kernel(
    const int* __restrict__ sel, const float* __restrict__ selscore,
    int* __restrict__ slot2pos, float* __restrict__ slot_score,
    int* __restrict__ counts, int* __restrict__ offsets) {
  __shared__ int hist[NE * 1024];
  __shared__ int tot[NE];
  __shared__ int offs[NE];
  int tid = threadIdx.x;
  int sl[16];
  int h[NE];
#pragma unroll
  for (int e = 0; e < NE; e++) h[e] = 0;
#pragma unroll
  for (int j = 0; j < 4; j++) {
    int4 v = ((const int4*)sel)[tid * 4 + j];
    sl[j * 4 + 0] = v.x; sl[j * 4 + 1] = v.y;
    sl[j * 4 + 2] = v.z; sl[j * 4 + 3] = v.w;
  }
#pragma unroll
  for (int i = 0; i < 16; i++)
#pragma unroll
    for (int e = 0; e < NE; e++) h[e] += (sl[i] == e) ? 1 : 0;
#pragma unroll
  for (int e = 0; e < NE; e++) hist[e * 1024 + tid] = h[e];
  __syncthreads();
  int wid = tid >> 6, lane = tid & 63;
  if (wid < NE) {
    int e = wid;
    int vals[16];
    int lsum = 0;
#pragma unroll
    for (int i = 0; i < 16; i++) {
      int v = hist[e * 1024 + lane * 16 + i];
      vals[i] = lsum;
      lsum += v;
    }
    int incl = lsum;
#pragma unroll
    for (int off = 1; off < 64; off <<= 1) {
      int v = __shfl_up(incl, off);
      if (lane >= off) incl += v;
    }
    int excl = incl - lsum;
#pragma unroll
    for (int i = 0; i < 16; i++) hist[e * 1024 + lane * 16 + i] = vals[i] + excl;
    if (lane == 63) tot[e] = incl;
  }
  __syncthreads();
  if (tid == 0) {
    int acc = 0;
    for (int e = 0; e < NE; e++) {
      offs[e] = acc;
      offsets[e] = acc;
      counts[e] = tot[e];
      acc += (tot[e] + 127) & ~127;   // 128-align every segment
    }
  }
  __syncthreads();
  int base[NE];
#pragma unroll
  for (int e = 0; e < NE; e++) base[e] = offs[e] + hist[e * 1024 + tid];
#pragma unroll
  for (int i = 0; i < 16; i++) {
    int slot = tid * 16 + i;
    int e = sl[i];
    int pos = 0;
#pragma unroll
    for (int k = 0; k < NE; k++) pos += (e == k) ? base[k] : 0;
#pragma unroll
    for (int k = 0; k < NE; k++) base[k] += (e == k) ? 1 : 0;
    slot2pos[slot] = pos;
    slot_score[pos] = selscore[slot];
  }
}

// ---------------- gather: slot -> blocked row pos of bf16(s*x) ---------------
// reads the router's blocked bf16 xb (half the bytes of fp32 x, L2-warm)
__global__ __launch_bounds__(256) void gather_kernel(
    const u16* __restrict__ xb, const float* __restrict__ selscore,
    const int* __restrict__ slot2pos, u16* __restrict__ routed) {
  int s = blockIdx.x * 4 + (threadIdx.x >> 6);
  int lane = threadIdx.x & 63;
  int pos = slot2pos[s];
  float sc = selscore[s];
  int t = s >> 1;
#pragma unroll
  for (int j = 0; j < 4; j++) {
    int c = j * 256 + lane * 4;
    uint2 v = *(const uint2*)&xb[ablk(t, c)];
    uint2 p;
    p.x = pack2(bflo(v.x) * sc, bfhi(v.x) * sc);
    p.y = pack2(bflo(v.y) * sc, bfhi(v.y) * sc);
    *(uint2*)&routed[ablk(pos, c)] = p;
  }
}

// ============================================================================
// Pipelined GEMM core (both kernels):
//  block = 256 rows x 128 cols, 4 waves (wy 2 x wx 1+1), wave tile 128x64,
//  mfma 32x32x16, BK=32. Staging: 24 KB/K-tile via 6x global_load_lds(16B)
//  per thread into 3 LDS buffers (72 KB). Counted vmcnt pipeline:
//    prologue: STAGE(t0), STAGE(t1)
//    iter t:   vmcnt(6)+barrier  -> tile t resident for all waves
//              STAGE(t+2)        -> into buffer of tile t-1 (reads done, C1)
//              COMPUTE(t)
//    last:     vmcnt(0)+barrier; COMPUTE
//  Loads for tiles t+1/t+2 stay in flight across barriers (T4: never drain 0).
//  LDS-read/MFMA = 0.75 KB/MFMA (vs 1 KB before) -> LDS-BW cap ~68% MfmaUtil.
// ============================================================================

// per-buffer u16 elems: A half0 4096 | A half1 4096 | B sec0 2048 | B sec1 2048
#define BUFE 12288

#define PIPE_STAGE(B, KT, pA, pB0, pB1)                        \
  do {                                                         \
    u16* Lb = &lds[(B) * BUFE];                                \
    const u16* a_ = (pA) + (size_t)(KT) * 4096;                \
    gload16(a_, Lb + tid * 8);                                 \
    gload16(a_ + 2048, Lb + 2048 + tid * 8);                   \
    gload16(a_ + 32 * 4096, Lb + 4096 + tid * 8);              \
    gload16(a_ + 32 * 4096 + 2048, Lb + 6144 + tid * 8);       \
    gload16((pB0) + (size_t)(KT) * 2048, Lb + 8192 + tid * 8); \
    gload16((pB1) + (size_t)(KT) * 2048, Lb + 10240 + tid * 8);\
  } while (0)

#define PIPE_COMPUTE(B)                                             \
  do {                                                              \
    const u16* La = &lds[(B) * BUFE] + wy * 4096;                   \
    const u16* Lw = &lds[(B) * BUFE] + 8192 + wx * 2048;            \
    _Pragma("unroll")                                               \
    for (int s = 0; s < 2; s++) {                                   \
      int kc = 2 * s + l5;                                          \
      bf16x8 b0 = *(const bf16x8*)&Lw[(kc * 64 + l31) * 8];         \
      bf16x8 b1 = *(const bf16x8*)&Lw[(kc * 64 + 32 + l31) * 8];    \
      _Pragma("unroll")                                             \
      for (int i = 0; i < 4; i++) {                                 \
        bf16x8 a = *(const bf16x8*)&La[(kc * 128 + i * 32 + l31) * 8]; \
        acc[i][0] = MFMA32(a, b0, acc[i][0]);                       \
        acc[i][1] = MFMA32(a, b1, acc[i][1]);                       \
      }                                                             \
    }                                                               \
  } while (0)

#define PIPE_LOOP(pA, pB0, pB1)                 \
  PIPE_STAGE(0, 0, pA, pB0, pB1);               \
  PIPE_STAGE(1, 1, pA, pB0, pB1);               \
  {                                             \
    int c0 = 0, c1 = 1, c2 = 2;                 \
    for (int kt = 0; kt < 31; ++kt) {           \
      PIPE_SYNC(6);                             \
      if (kt < 30) PIPE_STAGE(c2, kt + 2, pA, pB0, pB1); \
      PIPE_COMPUTE(c0);                         \
      int tmp = c0; c0 = c1; c1 = c2; c2 = tmp; \
    }                                           \
    PIPE_SYNC(0);                               \
    PIPE_COMPUTE(c0);                           \
  }

// ---------------- dual GLU GEMM: merged B = [W1-tile | W3-tile] --------------
// wx=0 waves compute h1 = A@W1^T, wx=1 waves compute h3 = A@W3^T for the SAME
// 64 H-cols; epilogue exchanges h1 through LDS and writes silu(h1)*h3.
__global__ __launch_bounds__(256, 2) void dual_glu_gemm(
    const u16* __restrict__ A, const u16* __restrict__ W1,
    const u16* __restrict__ W3, u16* __restrict__ Hout,
    const u16* __restrict__ As, const u16* __restrict__ SW1,
    const u16* __restrict__ SW3, u16* __restrict__ Hs,
    const int* __restrict__ seg_off, const int* __restrict__ seg_cnt) {
  int z = blockIdx.z;
  const u16 *Ap, *w1p, *w3p;
  u16* Hp;
  int soff, scnt;
  if (z < NE) {
    soff = seg_off[z]; scnt = seg_cnt[z];
    Ap = A;
    w1p = W1 + (size_t)z * HIDSZ * DIMSZ;
    w3p = W3 + (size_t)z * HIDSZ * DIMSZ;
    Hp = Hout;
  } else {
    soff = 0; scnt = T_TOK;
    Ap = As; w1p = SW1; w3p = SW3;
    Hp = Hs;
  }
  int mbase = blockIdx.y * 256;
  if (mbase >= scnt) return;
  int hx = blockIdx.x;                       // 64-col H tile

  __shared__ u16 lds[3 * BUFE];              // 72 KB

  int tid = threadIdx.x;
  int lane = tid & 63;
  int wid = tid >> 6;
  int wy = wid >> 1, wx = wid & 1;
  int l5 = lane >> 5, l31 = lane & 31;

  const u16* pA = Ap + ((size_t)((soff + mbase) >> 7) * 32) * 4096 + tid * 8;
  const u16* pB1 = w1p + ((size_t)hx * 32) * 2048 + tid * 8;
  const u16* pB3 = w3p + ((size_t)hx * 32) * 2048 + tid * 8;

  f32x16 acc[4][2];
#pragma unroll
  for (int i = 0; i < 4; i++) { acc[i][0] = (f32x16)0.f; acc[i][1] = (f32x16)0.f; }

  PIPE_LOOP(pA, pB1, pB3);

  // ---- epilogue: exchange h1 (wx=0) via LDS, combine on wx=1 ----
  __syncthreads();                          // all LDS reads of the loop done
  float* ex = (float*)lds;                  // 256 x 64 f32 = 64 KB (fits 72)
  if (wx == 0) {
#pragma unroll
    for (int i = 0; i < 4; i++)
#pragma unroll
      for (int j = 0; j < 2; j++)
#pragma unroll
        for (int r = 0; r < 16; r++) {
          int row = wy * 128 + i * 32 + (r & 3) + 8 * (r >> 2) + 4 * l5;
          ex[row * 64 + j * 32 + l31] = acc[i][j][r];
        }
  }
  __syncthreads();
  if (wx == 1) {
#pragma unroll
    for (int i = 0; i < 4; i++)
#pragma unroll
      for (int j = 0; j < 2; j++)
#pragma unroll
        for (int r = 0; r < 16; r++) {
          int row = wy * 128 + i * 32 + (r & 3) + 8 * (r >> 2) + 4 * l5;
          int grow = mbase + row;
          if (grow < scnt) {
            float h1 = ex[row * 64 + j * 32 + l31];
            Hp[ablk(soff + grow, hx * 64 + j * 32 + l31)] =
                f2bf(silu_f(h1) * acc[i][j][r]);
          }
        }
  }
}

// ---------------- GEMM2: Out = (A @ W^T) * scale -----------------------------
__global__ __launch_bounds__(256, 2) void gemm2_kernel(
    const u16* __restrict__ A, const u16* __restrict__ W, u16* __restrict__ OutB,
    const u16* __restrict__ As, const u16* __restrict__ SW, float* __restrict__ OutF,
    const float* __restrict__ scale, const int* __restrict__ seg_off,
    const int* __restrict__ seg_cnt) {
  int z = blockIdx.z;
  const u16 *Ap, *wp;
  int soff, scnt;
  if (z < NE) {
    soff = seg_off[z]; scnt = seg_cnt[z];
    Ap = A; wp = W + (size_t)z * DIMSZ * HIDSZ;
  } else {
    soff = 0; scnt = T_TOK;
    Ap = As; wp = SW;
  }
  int mbase = blockIdx.y * 256;
  if (mbase >= scnt) return;
  int nbase = blockIdx.x * 128;

  __shared__ u16 lds[3 * BUFE];

  int tid = threadIdx.x;
  int lane = tid & 63;
  int wid = tid >> 6;
  int wy = wid >> 1, wx = wid & 1;
  int l5 = lane >> 5, l31 = lane & 31;

  const u16* pA = Ap + ((size_t)((soff + mbase) >> 7) * 32) * 4096 + tid * 8;
  const u16* pB0 = wp + ((size_t)(nbase >> 6) * 32) * 2048 + tid * 8;
  const u16* pB1 = pB0 + (size_t)32 * 2048;

  f32x16 acc[4][2];
#pragma unroll
  for (int i = 0; i < 4; i++) { acc[i][0] = (f32x16)0.f; acc[i][1] = (f32x16)0.f; }

  PIPE_LOOP(pA, pB0, pB1);

#pragma unroll
  for (int i = 0; i < 4; i++)
#pragma unroll
    for (int j = 0; j < 2; j++) {
      int colg = nbase + wx * 64 + j * 32 + l31;
#pragma unroll
      for (int r = 0; r < 16; r++) {
        int rowl = (r & 3) + 8 * (r >> 2) + 4 * l5;
        int grow = mbase + wy * 128 + i * 32 + rowl;
        if (grow < scnt) {
          size_t idx = (size_t)(soff + grow) * DIMSZ + colg;
          if (z < NE) {
            OutB[idx] = f2bf(acc[i][j][r] * scale[soff + grow]);
          } else {
            OutF[idx] = acc[i][j][r];
          }
        }
      }
    }
}

// ---------------- combine: out[t] += Or[pos(t,0)] + Or[pos(t,1)] -------------
__global__ __launch_bounds__(256) void combine_kernel(
    float* __restrict__ out, const u16* __restrict__ Orb,
    const int* __restrict__ slot2pos) {
  int t = blockIdx.x;
  int d = threadIdx.x * 4;
  int p0 = slot2pos[t * 2];
  int p1 = slot2pos[t * 2 + 1];
  float4 o = *(float4*)&out[(size_t)t * DIMSZ + d];
  uint2 a = *(const uint2*)&Orb[(size_t)p0 * DIMSZ + d];
  uint2 b = *(const uint2*)&Orb[(size_t)p1 * DIMSZ + d];
  o.x += bflo(a.x) + bflo(b.x);
  o.y += bfhi(a.x) + bfhi(b.x);
  o.z += bflo(a.y) + bflo(b.y);
  o.w += bfhi(a.y) + bfhi(b.y);
  *(float4*)&out[(size_t)t * DIMSZ + d] = o;
}

extern "C" void kernel_launch(void* const* d_in, const int* in_sizes, int n_in,
                              void* d_out, int out_size, void* d_ws, size_t ws_size,
                              hipStream_t stream) {
  const float* x = (const float*)d_in[0];
  const float* gw = (const float*)d_in[1];
  const float* w1 = (const float*)d_in[2];
  const float* w2 = (const float*)d_in[3];
  const float* w3 = (const float*)d_in[4];
  const float* sw1 = (const float*)d_in[5];
  const float* sw2 = (const float*)d_in[6];
  const float* sw3 = (const float*)d_in[7];
  const float* bias = (const float*)d_in[8];
  float* out = (float*)d_out;

  uint8_t* ws = (uint8_t*)d_ws;
  size_t off = 0;
  auto alloc = [&](size_t b) { size_t o = off; off += (b + 255) & ~(size_t)255; return o; };

  size_t ctrl = alloc(256);
  int* counts = (int*)(ws + ctrl);
  int* offsets = counts + 16;
  int* sel = (int*)(ws + alloc((size_t)NSLOT * 4));
  float* selscore = (float*)(ws + alloc((size_t)NSLOT * 4));
  float* slot_score = (float*)(ws + alloc((size_t)NPAD * 4));
  int* slot2pos = (int*)(ws + alloc((size_t)NSLOT * 4));
  u16* xb = (u16*)(ws + alloc((size_t)T_TOK * DIMSZ * 2));
  u16* routed = (u16*)(ws + alloc((size_t)NPAD * DIMSZ * 2));
  u16* Hbuf = (u16*)(ws + alloc((size_t)NPAD * HIDSZ * 2));
  u16* Orb = (u16*)(ws + alloc((size_t)NPAD * DIMSZ * 2));
  u16* Hs = (u16*)(ws + alloc((size_t)T_TOK * HIDSZ * 2));
  u16* w1b = (u16*)(ws + alloc((size_t)NE * HIDSZ * DIMSZ * 2));
  u16* w2b = (u16*)(ws + alloc((size_t)NE * DIMSZ * HIDSZ * 2));
  u16* w3b = (u16*)(ws + alloc((size_t)NE * HIDSZ * DIMSZ * 2));
  u16* sw1b = (u16*)(ws + alloc((size_t)HIDSZ * DIMSZ * 2));
  u16* sw2b = (u16*)(ws + alloc((size_t)DIMSZ * HIDSZ * 2));
  u16* sw3b = (u16*)(ws + alloc((size_t)HIDSZ * DIMSZ * 2));

  // weight conversion fp32 row-major -> bf16 blocked tiles (single launch)
  convert_blocked<<<dim3((NE + 1) * 16 * 32, 3), 256, 0, stream>>>(
      w1, w2, w3, sw1, sw2, sw3, w1b, w2b, w3b, sw1b, sw2b, sw3b);

  router_kernel<<<T_TOK / 4, 256, 0, stream>>>(x, gw, bias, sel, selscore, xb);
  rank_kernel<<<1, 1024, 0, stream>>>(sel, selscore, slot2pos, slot_score,
                                      counts, offsets);
  gather_kernel<<<NSLOT / 4, 256, 0, stream>>>(xb, selscore, slot2pos, routed);

  // unified GEMMs: z = 0..7 routed experts, z = 8 shared expert
  dual_glu_gemm<<<dim3(16, 32, NE + 1), 256, 0, stream>>>(
      routed, w1b, w3b, Hbuf, xb, sw1b, sw3b, Hs, offsets, counts);
  gemm2_kernel<<<dim3(8, 32, NE + 1), 256, 0, stream>>>(
      Hbuf, w2b, Orb, Hs, sw2b, out, slot_score, offsets, counts);

  // combine routed contributions into shared output
  combine_kernel<<<T_TOK, 256, 0, stream>>>(out, Orb, slot2pos);
}

// Round 2
// 495.022 us; speedup vs baseline: 1.0791x; 1.0791x over previous
//
#include <hip/hip_runtime.h>
#include <stdint.h>

typedef unsigned short u16;
typedef unsigned int u32;

#define T_TOK 8192      // B*S tokens
#define DIMSZ 1024
#define HIDSZ 1024
#define NE 8
#define NSLOT (T_TOK * 2)
#define NPAD (NSLOT + 1024)   // segment-aligned slot capacity

typedef __attribute__((ext_vector_type(8))) __bf16 bf16x8;
typedef __attribute__((ext_vector_type(16))) float f32x16;

#define MFMA32(a, b, c) __builtin_amdgcn_mfma_f32_32x32x16_bf16(a, b, c, 0, 0, 0)

// ---- blocked tile layouts (all GEMM operands, K = 1024, KT = 32) ----------
// A (activations, 128-row tiles):  [mt][kt][kc][row(128)][8]  (8 KB / tile)
// W (weights, 64-row tiles):       [nt][kt][kc][col(64)][8]   (4 KB / tile)
__device__ __forceinline__ size_t ablk(int pos, int c) {
  return ((((size_t)(pos >> 7) * 32 + (c >> 5)) * 4 + ((c >> 3) & 3)) * 128 +
          (pos & 127)) * 8 + (c & 7);
}

__device__ __forceinline__ u16 f2bf(float f) {
  u32 u = __builtin_bit_cast(u32, f);
  u += 0x7FFFu + ((u >> 16) & 1u);   // RNE
  return (u16)(u >> 16);
}
__device__ __forceinline__ float bflo(u32 v) { return __builtin_bit_cast(float, v << 16); }
__device__ __forceinline__ float bfhi(u32 v) { return __builtin_bit_cast(float, v & 0xffff0000u); }
__device__ __forceinline__ u32 pack2(float a, float b) {
  return (u32)f2bf(a) | ((u32)f2bf(b) << 16);
}
__device__ __forceinline__ float silu_f(float v) { return v / (1.f + expf(-v)); }

// ---- async global->LDS, 16 B per lane (global_load_lds_dwordx4) -----------
__device__ __forceinline__ void gload16(const void* g, void* l) {
  __builtin_amdgcn_global_load_lds(
      (const __attribute__((address_space(1))) unsigned int*)g,
      (__attribute__((address_space(3))) unsigned int*)l, 16, 0, 0);
}

// counted-vmcnt barrier: wait until <=N of this wave's global_load_lds remain
// outstanding, then s_barrier (single asm so nothing schedules between).
#define PIPE_SYNC(N) asm volatile("s_waitcnt vmcnt(" #N ")\n\ts_barrier" ::: "memory")

// ---------------- weight convert: fp32 row-major -> bf16 blocked (1 launch) --
__global__ __launch_bounds__(256) void convert_blocked(
    const float* __restrict__ s0, const float* __restrict__ s1,
    const float* __restrict__ s2, const float* __restrict__ ss0,
    const float* __restrict__ ss1, const float* __restrict__ ss2,
    u16* __restrict__ d0, u16* __restrict__ d1, u16* __restrict__ d2,
    u16* __restrict__ ds0, u16* __restrict__ ds1, u16* __restrict__ ds2) {
  __shared__ u16 lt[2048];
  int t = blockIdx.x;
  const float* s;
  u16* d;
  if (t < NE * 16 * 32) {
    s = (blockIdx.y == 0) ? s0 : (blockIdx.y == 1) ? s1 : s2;
    d = (blockIdx.y == 0) ? d0 : (blockIdx.y == 1) ? d1 : d2;
  } else {
    t -= NE * 16 * 32;
    s = (blockIdx.y == 0) ? ss0 : (blockIdx.y == 1) ? ss1 : ss2;
    d = (blockIdx.y == 0) ? ds0 : (blockIdx.y == 1) ? ds1 : ds2;
  }
  int rt = t >> 5, kt = t & 31;           // 64-row group, k-tile
  const float* sp = s + (size_t)rt * 64 * 1024 + kt * 32;
  int nl = threadIdx.x >> 2, k0 = (threadIdx.x & 3) * 8;
  float4 a = *(const float4*)(sp + (size_t)nl * 1024 + k0);
  float4 b = *(const float4*)(sp + (size_t)nl * 1024 + k0 + 4);
  uint4 p;
  p.x = pack2(a.x, a.y); p.y = pack2(a.z, a.w);
  p.z = pack2(b.x, b.y); p.w = pack2(b.z, b.w);
  *(uint4*)&lt[(threadIdx.x & 3) * 512 + nl * 8] = p;   // [kc][col][8]
  __syncthreads();
  *(uint4*)(d + (size_t)t * 2048 + threadIdx.x * 8) = *(const uint4*)&lt[threadIdx.x * 8];
}

// ---------------- router: fp32 scores, top-2; emits blocked bf16(x) ----------
__global__ __launch_bounds__(256) void router_kernel(
    const float* __restrict__ x, const float* __restrict__ gw,
    const float* __restrict__ bias, int* __restrict__ sel,
    float* __restrict__ selscore, u16* __restrict__ xb) {
  int t = blockIdx.x * 4 + (threadIdx.x >> 6);
  int lane = threadIdx.x & 63;
  float a[NE];
#pragma unroll
  for (int e = 0; e < NE; e++) a[e] = 0.f;
#pragma unroll
  for (int j = 0; j < 4; j++) {
    int c = j * 256 + lane * 4;
    float4 xv = *(const float4*)&x[(size_t)t * DIMSZ + c];
    uint2 p;
    p.x = pack2(xv.x, xv.y);
    p.y = pack2(xv.z, xv.w);
    *(uint2*)&xb[ablk(t, c)] = p;
#pragma unroll
    for (int e = 0; e < NE; e++) {
      float4 gv = *(const float4*)&gw[e * DIMSZ + c];
      a[e] = fmaf(xv.x, gv.x, fmaf(xv.y, gv.y, fmaf(xv.z, gv.z, fmaf(xv.w, gv.w, a[e]))));
    }
  }
#pragma unroll
  for (int off = 1; off < 64; off <<= 1)
#pragma unroll
    for (int e = 0; e < NE; e++) a[e] += __shfl_xor(a[e], off);
  if (lane == 0) {
    float s[NE], b[NE];
#pragma unroll
    for (int e = 0; e < NE; e++) {
      s[e] = 1.f / (1.f + expf(-a[e]));
      b[e] = s[e] + bias[e];
    }
    int e1 = 0; float v1 = b[0];
#pragma unroll
    for (int e = 1; e < NE; e++) if (b[e] > v1) { v1 = b[e]; e1 = e; }
    int e2 = -1; float v2 = -1e30f;
#pragma unroll
    for (int e = 0; e < NE; e++) if (e != e1 && b[e] > v2) { v2 = b[e]; e2 = e; }
    sel[t * 2] = e1; sel[t * 2 + 1] = e2;
    selscore[t * 2] = s[e1];       // ROUTE_SCALE == 1
    selscore[t * 2 + 1] = s[e2];
  }
}

// ---------------- rank: atomic-free permutation; 128-aligned segments --------
__global__ __launch_bounds__(1024) void rank_kernel(
    const int* __restrict__ sel, const float* __restrict__ selscore,
    int* __restrict__ slot2pos, float* __restrict__ slot_score,
    int* __restrict__ counts, int* __restrict__ offsets) {
  __shared__ int hist[NE * 1024];
  __shared__ int tot[NE];
  __shared__ int offs[NE];
  int tid = threadIdx.x;
  int sl[16];
  int h[NE];
#pragma unroll
  for (int e = 0; e < NE; e++) h[e] = 0;
#pragma unroll
  for (int j = 0; j < 4; j++) {
    int4 v = ((const int4*)sel)[tid * 4 + j];
    sl[j * 4 + 0] = v.x; sl[j * 4 + 1] = v.y;
    sl[j * 4 + 2] = v.z; sl[j * 4 + 3] = v.w;
  }
#pragma unroll
  for (int i = 0; i < 16; i++)
#pragma unroll
    for (int e = 0; e < NE; e++) h[e] += (sl[i] == e) ? 1 : 0;
#pragma unroll
  for (int e = 0; e < NE; e++) hist[e * 1024 + tid] = h[e];
  __syncthreads();
  int wid = tid >> 6, lane = tid & 63;
  if (wid < NE) {
    int e = wid;
    int vals[16];
    int lsum = 0;
#pragma unroll
    for (int i = 0; i < 16; i++) {
      int v = hist[e * 1024 + lane * 16 + i];
      vals[i] = lsum;
      lsum += v;
    }
    int incl = lsum;
#pragma unroll
    for (int off = 1; off < 64; off <<= 1) {
      int v = __shfl_up(incl, off);
      if (lane >= off) incl += v;
    }
    int excl = incl - lsum;
#pragma unroll
    for (int i = 0; i < 16; i++) hist[e * 1024 + lane * 16 + i] = vals[i] + excl;
    if (lane == 63) tot[e] = incl;
  }
  __syncthreads();
  if (tid == 0) {
    int acc = 0;
    for (int e = 0; e < NE; e++) {
      offs[e] = acc;
      offsets[e] = acc;
      counts[e] = tot[e];
      acc += (tot[e] + 127) & ~127;   // 128-align every segment
    }
  }
  __syncthreads();
  int base[NE];
#pragma unroll
  for (int e = 0; e < NE; e++) base[e] = offs[e] + hist[e * 1024 + tid];
#pragma unroll
  for (int i = 0; i < 16; i++) {
    int slot = tid * 16 + i;
    int e = sl[i];
    int pos = 0;
#pragma unroll
    for (int k = 0; k < NE; k++) pos += (e == k) ? base[k] : 0;
#pragma unroll
    for (int k = 0; k < NE; k++) base[k] += (e == k) ? 1 : 0;
    slot2pos[slot] = pos;
    slot_score[pos] = selscore[slot];
  }
}

// ---------------- gather: slot -> blocked row pos of bf16(s*x) ---------------
__global__ __launch_bounds__(256) void gather_kernel(
    const u16* __restrict__ xb, const float* __restrict__ selscore,
    const int* __restrict__ slot2pos, u16* __restrict__ routed) {
  int s = blockIdx.x * 4 + (threadIdx.x >> 6);
  int lane = threadIdx.x & 63;
  int pos = slot2pos[s];
  float sc = selscore[s];
  int t = s >> 1;
#pragma unroll
  for (int j = 0; j < 4; j++) {
    int c = j * 256 + lane * 4;
    uint2 v = *(const uint2*)&xb[ablk(t, c)];
    uint2 p;
    p.x = pack2(bflo(v.x) * sc, bfhi(v.x) * sc);
    p.y = pack2(bflo(v.y) * sc, bfhi(v.y) * sc);
    *(uint2*)&routed[ablk(pos, c)] = p;
  }
}

// ============================================================================
// Pipelined GEMM core (both GEMM kernels):
//  512 threads = 8 waves (wy2 x wq4), block tile 128 rows x 128 cols,
//  wave tile 64 rows x 32 cols, mfma 32x32x16, K-tile = 32.
//  LDS: 3 buffers x 16 KB (A 8 KB + B 8 KB) = 48 KB -> 2 blocks/CU at
//  <=128 VGPR (launch_bounds(512,4)) -> 16 waves/CU = 4/SIMD.
//  Staging: 2 x global_load_lds(16B)/thread/K-tile (DMA, no VALU repack).
//  Counted-vmcnt distance-2 pipeline:
//    prologue: STAGE(t0->b0), STAGE(t1->b1)            [4 in flight]
//    iter t:   SYNC vmcnt(2)+barrier  -> tile t resident for all waves,
//                                        tile t+1 loads stay in flight
//              STAGE(t+2 -> buf of t-1)  (prior reads done: one barrier ago)
//              setprio(1); 4 MFMA; setprio(0)
//    tail:     SYNC(2); compute; SYNC(0); compute
// ============================================================================
#define BUFE 8192   // u16 per buffer: A[kc4][row128][8] | B[sec2][kc4][col64][8]

#define PIPE_STAGE(B, KT)                                         \
  do {                                                            \
    u16* Lb = &lds[(B) * BUFE];                                   \
    gload16(pA + (size_t)(KT) * 4096, Lb + tid * 8);              \
    gload16(pBm + (size_t)(KT) * 2048, Lb + bdst);                \
  } while (0)

#define PIPE_COMPUTE(B)                                               \
  do {                                                                \
    const u16* Lb = &lds[(B) * BUFE];                                 \
    _Pragma("unroll")                                                 \
    for (int c = 0; c < 2; c++) {                                     \
      int ko = 2 * c + l5;                                            \
      bf16x8 b = *(const bf16x8*)&Lb[4096 + bsel + ko * 512 + l31 * 8]; \
      bf16x8 a0 = *(const bf16x8*)&Lb[ko * 1024 + wy * 512 + l31 * 8];  \
      bf16x8 a1 = *(const bf16x8*)&Lb[ko * 1024 + wy * 512 + 256 + l31 * 8]; \
      acc[0] = MFMA32(a0, b, acc[0]);                                 \
      acc[1] = MFMA32(a1, b, acc[1]);                                 \
    }                                                                 \
  } while (0)

#define PIPE_LOOP()                                                   \
  PIPE_STAGE(0, 0);                                                   \
  PIPE_STAGE(1, 1);                                                   \
  {                                                                   \
    int c0 = 0, c1 = 1, c2 = 2;                                       \
    for (int t = 0; t < 30; ++t) {                                    \
      PIPE_SYNC(2);                                                   \
      PIPE_STAGE(c2, t + 2);                                          \
      __builtin_amdgcn_s_setprio(1);                                  \
      PIPE_COMPUTE(c0);                                               \
      __builtin_amdgcn_s_setprio(0);                                  \
      int tm = c0; c0 = c1; c1 = c2; c2 = tm;                         \
    }                                                                 \
    PIPE_SYNC(2);                                                     \
    __builtin_amdgcn_s_setprio(1);                                    \
    PIPE_COMPUTE(c0);                                                 \
    __builtin_amdgcn_s_setprio(0);                                    \
    c0 = c1;                                                          \
    PIPE_SYNC(0);                                                     \
    __builtin_amdgcn_s_setprio(1);                                    \
    PIPE_COMPUTE(c0);                                                 \
    __builtin_amdgcn_s_setprio(0);                                    \
  }

// ---------------- dual GLU GEMM: B = [W1 64-col unit | W3 64-col unit] -------
// wq<2 waves compute h1 = A@W1^T cols (wq&1)*32.., wq>=2 compute h3 same cols;
// epilogue exchanges h1 via 32 KB f32 LDS region, h3 waves write silu(h1)*h3.
__global__ __launch_bounds__(512, 4) void dual_glu_gemm(
    const u16* __restrict__ A, const u16* __restrict__ W1,
    const u16* __restrict__ W3, u16* __restrict__ Hout,
    const u16* __restrict__ As, const u16* __restrict__ SW1,
    const u16* __restrict__ SW3, u16* __restrict__ Hs,
    const int* __restrict__ seg_off, const int* __restrict__ seg_cnt) {
  int z = blockIdx.z;
  const u16 *Ap, *w1p, *w3p;
  u16* Hp;
  int soff, scnt;
  if (z < NE) {
    soff = seg_off[z]; scnt = seg_cnt[z];
    Ap = A;
    w1p = W1 + (size_t)z * HIDSZ * DIMSZ;
    w3p = W3 + (size_t)z * HIDSZ * DIMSZ;
    Hp = Hout;
  } else {
    soff = 0; scnt = T_TOK;
    Ap = As; w1p = SW1; w3p = SW3;
    Hp = Hs;
  }
  int mbase = blockIdx.y * 128;
  if (mbase >= scnt) return;
  int hx = blockIdx.x;                       // 64-col H tile

  __shared__ u16 lds[3 * BUFE];              // 48 KB

  int tid = threadIdx.x;
  int lane = tid & 63;
  int wid = tid >> 6;
  int wy = wid >> 2, wq = wid & 3;           // wy: 64-row half, wq: B slot
  int l5 = lane >> 5, l31 = lane & 31;

  const u16* pA = Ap + (size_t)((soff + mbase) >> 7) * 32 * 4096 + tid * 8;
  const u16* w1u = w1p + (size_t)hx * 32 * 2048;
  const u16* w3u = w3p + (size_t)hx * 32 * 2048;
  const u16* pBm = ((tid >> 8) ? w3u : w1u) + (tid & 255) * 8;
  int bdst = 4096 + (tid >> 8) * 2048 + (tid & 255) * 8;
  int bsel = (wq >> 1) * 2048 + (wq & 1) * 256;

  f32x16 acc[2];
  acc[0] = (f32x16)0.f; acc[1] = (f32x16)0.f;

  PIPE_LOOP();

  // ---- epilogue: exchange h1 (wq<2) via LDS f32 region, combine on wq>=2 ----
  __syncthreads();
  float* ex = (float*)lds;                   // 4 regions x 64x32 f32 = 32 KB
  int region = wy * 2 + (wq & 1);
  if (wq < 2) {
#pragma unroll
    for (int i = 0; i < 2; i++)
#pragma unroll
      for (int r = 0; r < 16; r++) {
        int rowl = (r & 3) + 8 * (r >> 2) + 4 * l5;
        ex[region * 2048 + (i * 32 + rowl) * 32 + l31] = acc[i][r];
      }
  }
  __syncthreads();
  if (wq >= 2) {
#pragma unroll
    for (int i = 0; i < 2; i++)
#pragma unroll
      for (int r = 0; r < 16; r++) {
        int rowl = (r & 3) + 8 * (r >> 2) + 4 * l5;
        int grow = mbase + wy * 64 + i * 32 + rowl;
        if (grow < scnt) {
          float h1 = ex[region * 2048 + (i * 32 + rowl) * 32 + l31];
          Hp[ablk(soff + grow, hx * 64 + (wq & 1) * 32 + l31)] =
              f2bf(silu_f(h1) * acc[i][r]);
        }
      }
  }
}

// ---------------- GEMM2: Out = (A @ W^T) * scale -----------------------------
__global__ __launch_bounds__(512, 4) void gemm2_kernel(
    const u16* __restrict__ A, const u16* __restrict__ W, u16* __restrict__ OutB,
    const u16* __restrict__ As, const u16* __restrict__ SW, float* __restrict__ OutF,
    const float* __restrict__ scale, const int* __restrict__ seg_off,
    const int* __restrict__ seg_cnt) {
  int z = blockIdx.z;
  const u16 *Ap, *wp;
  int soff, scnt;
  if (z < NE) {
    soff = seg_off[z]; scnt = seg_cnt[z];
    Ap = A; wp = W + (size_t)z * DIMSZ * HIDSZ;
  } else {
    soff = 0; scnt = T_TOK;
    Ap = As; wp = SW;
  }
  int mbase = blockIdx.y * 128;
  if (mbase >= scnt) return;
  int nbase = blockIdx.x * 128;

  __shared__ u16 lds[3 * BUFE];

  int tid = threadIdx.x;
  int lane = tid & 63;
  int wid = tid >> 6;
  int wy = wid >> 2, wq = wid & 3;
  int l5 = lane >> 5, l31 = lane & 31;

  const u16* pA = Ap + (size_t)((soff + mbase) >> 7) * 32 * 4096 + tid * 8;
  const u16* nt0 = wp + (size_t)(nbase >> 6) * 32 * 2048;
  const u16* pBm = nt0 + (size_t)(tid >> 8) * 32 * 2048 + (tid & 255) * 8;
  int bdst = 4096 + (tid >> 8) * 2048 + (tid & 255) * 8;
  int bsel = (wq >> 1) * 2048 + (wq & 1) * 256;

  f32x16 acc[2];
  acc[0] = (f32x16)0.f; acc[1] = (f32x16)0.f;

  PIPE_LOOP();

#pragma unroll
  for (int i = 0; i < 2; i++) {
    int colg = nbase + wq * 32 + l31;
#pragma unroll
    for (int r = 0; r < 16; r++) {
      int rowl = (r & 3) + 8 * (r >> 2) + 4 * l5;
      int grow = mbase + wy * 64 + i * 32 + rowl;
      if (grow < scnt) {
        size_t idx = (size_t)(soff + grow) * DIMSZ + colg;
        if (z < NE) {
          OutB[idx] = f2bf(acc[i][r] * scale[soff + grow]);
        } else {
          OutF[idx] = acc[i][r];
        }
      }
    }
  }
}

// ---------------- combine: out[t] += Or[pos(t,0)] + Or[pos(t,1)] -------------
__global__ __launch_bounds__(256) void combine_kernel(
    float* __restrict__ out, const u16* __restrict__ Orb,
    const int* __restrict__ slot2pos) {
  int t = blockIdx.x;
  int d = threadIdx.x * 4;
  int p0 = slot2pos[t * 2];
  int p1 = slot2pos[t * 2 + 1];
  float4 o = *(float4*)&out[(size_t)t * DIMSZ + d];
  uint2 a = *(const uint2*)&Orb[(size_t)p0 * DIMSZ + d];
  uint2 b = *(const uint2*)&Orb[(size_t)p1 * DIMSZ + d];
  o.x += bflo(a.x) + bflo(b.x);
  o.y += bfhi(a.x) + bfhi(b.x);
  o.z += bflo(a.y) + bflo(b.y);
  o.w += bfhi(a.y) + bfhi(b.y);
  *(float4*)&out[(size_t)t * DIMSZ + d] = o;
}

extern "C" void kernel_launch(void* const* d_in, const int* in_sizes, int n_in,
                              void* d_out, int out_size, void* d_ws, size_t ws_size,
                              hipStream_t stream) {
  const float* x = (const float*)d_in[0];
  const float* gw = (const float*)d_in[1];
  const float* w1 = (const float*)d_in[2];
  const float* w2 = (const float*)d_in[3];
  const float* w3 = (const float*)d_in[4];
  const float* sw1 = (const float*)d_in[5];
  const float* sw2 = (const float*)d_in[6];
  const float* sw3 = (const float*)d_in[7];
  const float* bias = (const float*)d_in[8];
  float* out = (float*)d_out;

  uint8_t* ws = (uint8_t*)d_ws;
  size_t off = 0;
  auto alloc = [&](size_t b) { size_t o = off; off += (b + 255) & ~(size_t)255; return o; };

  size_t ctrl = alloc(256);
  int* counts = (int*)(ws + ctrl);
  int* offsets = counts + 16;
  int* sel = (int*)(ws + alloc((size_t)NSLOT * 4));
  float* selscore = (float*)(ws + alloc((size_t)NSLOT * 4));
  float* slot_score = (float*)(ws + alloc((size_t)NPAD * 4));
  int* slot2pos = (int*)(ws + alloc((size_t)NSLOT * 4));
  u16* xb = (u16*)(ws + alloc((size_t)T_TOK * DIMSZ * 2));
  u16* routed = (u16*)(ws + alloc((size_t)NPAD * DIMSZ * 2));
  u16* Hbuf = (u16*)(ws + alloc((size_t)NPAD * HIDSZ * 2));
  u16* Orb = (u16*)(ws + alloc((size_t)NPAD * DIMSZ * 2));
  u16* Hs = (u16*)(ws + alloc((size_t)T_TOK * HIDSZ * 2));
  u16* w1b = (u16*)(ws + alloc((size_t)NE * HIDSZ * DIMSZ * 2));
  u16* w2b = (u16*)(ws + alloc((size_t)NE * DIMSZ * HIDSZ * 2));
  u16* w3b = (u16*)(ws + alloc((size_t)NE * HIDSZ * DIMSZ * 2));
  u16* sw1b = (u16*)(ws + alloc((size_t)HIDSZ * DIMSZ * 2));
  u16* sw2b = (u16*)(ws + alloc((size_t)DIMSZ * HIDSZ * 2));
  u16* sw3b = (u16*)(ws + alloc((size_t)HIDSZ * DIMSZ * 2));

  // weight conversion fp32 row-major -> bf16 blocked tiles (single launch)
  convert_blocked<<<dim3((NE + 1) * 16 * 32, 3), 256, 0, stream>>>(
      w1, w2, w3, sw1, sw2, sw3, w1b, w2b, w3b, sw1b, sw2b, sw3b);

  router_kernel<<<T_TOK / 4, 256, 0, stream>>>(x, gw, bias, sel, selscore, xb);
  rank_kernel<<<1, 1024, 0, stream>>>(sel, selscore, slot2pos, slot_score,
                                      counts, offsets);
  gather_kernel<<<NSLOT / 4, 256, 0, stream>>>(xb, selscore, slot2pos, routed);

  // unified GEMMs: z = 0..7 routed experts, z = 8 shared expert
  dual_glu_gemm<<<dim3(16, 64, NE + 1), 512, 0, stream>>>(
      routed, w1b, w3b, Hbuf, xb, sw1b, sw3b, Hs, offsets, counts);
  gemm2_kernel<<<dim3(8, 64, NE + 1), 512, 0, stream>>>(
      Hbuf, w2b, Orb, Hs, sw2b, out, slot_score, offsets, counts);

  // combine routed contributions into shared output
  combine_kernel<<<T_TOK, 256, 0, stream>>>(out, Orb, slot2pos);
}